// Round 1
// baseline (484.952 us; speedup 1.0000x reference)
//
#include <hip/hip_runtime.h>
#include <hip/hip_bf16.h>

#define CC 256   // input channels
#define OO 256   // output channels
#define HH 64
#define WW 64
#define HWH 4096 // H*W
#define PPB 32   // pixels per block (main kernel)
#define CCH 32   // c-chunk for weight staging
#define VPAD 36  // padded pixel stride in val_lds

// ---------------- transpose x: [N,C,H,W] -> xt [N,H*W,C] ----------------
__global__ __launch_bounds__(256) void transpose_x_kernel(
    const float* __restrict__ x, float* __restrict__ xt) {
  __shared__ float tile[32][33];
  int n  = blockIdx.z;
  int c0 = blockIdx.y * 32;
  int s0 = blockIdx.x * 32;      // flat h*W+w
  int tx = threadIdx.x;          // 0..31
  int ty = threadIdx.y;          // 0..7
  const float* xp = x + ((size_t)n * CC + c0) * HWH + s0;
#pragma unroll
  for (int i = ty; i < 32; i += 8)
    tile[i][tx] = xp[(size_t)i * HWH + tx];
  __syncthreads();
  float* op = xt + ((size_t)n * HWH + s0) * CC + c0;
#pragma unroll
  for (int i = ty; i < 32; i += 8)
    op[(size_t)i * CC + tx] = tile[tx][i];
}

// ------------- transpose weight: [O,C,9] -> wt [9][C][O] -------------
__global__ __launch_bounds__(256) void transpose_w_kernel(
    const float* __restrict__ w, float* __restrict__ wt) {
  int tid = blockIdx.x * 256 + threadIdx.x;   // 0 .. 589823
  int k = tid >> 16;
  int c = (tid >> 8) & 255;
  int o = tid & 255;
  wt[tid] = w[((size_t)o * CC + c) * 9 + k];
}

// ---------------- main fused deform-sample + GEMM ----------------
// grid: N*HW/PPB blocks of 256 threads.
// Each block: PPB consecutive pixels (same n), all 256 output channels.
// thread: lane = tid&63 -> o in [4*lane, 4*lane+3]; pg = tid>>6 -> pixels pg*8..pg*8+7
__global__ __launch_bounds__(256, 2) void deform_main_kernel(
    const float* __restrict__ xt, const float* __restrict__ wt,
    const float* __restrict__ off, float* __restrict__ out) {
  __shared__ __align__(16) float val_lds[CC * VPAD];       // [c][p] padded, 36 KB
  __shared__ __align__(16) float w_lds[CCH * OO];          // [ci][o], 32 KB
  __shared__ int   s_iy[PPB * 9], s_ix[PPB * 9];
  __shared__ float s_wy[PPB * 9], s_wx[PPB * 9];

  const int tid  = threadIdx.x;
  const int lane = tid & 63;
  const int pg   = tid >> 6;

  const int gp  = blockIdx.x * PPB;       // global pixel base
  const int n   = gp >> 12;               // /4096
  const int hw0 = gp & (HWH - 1);

  // ---- precompute per-(pixel,tap) sampling params ----
  for (int idx = tid; idx < PPB * 9; idx += 256) {
    int p = idx / 9;
    int k = idx - p * 9;
    int hw = hw0 + p;
    int h = hw >> 6, w = hw & 63;
    size_t ob = ((size_t)(n * HWH + hw)) * 18 + 2 * k;
    float dy = off[ob];
    float dx = off[ob + 1];
    float py = (float)(h + (k / 3) - 1) + dy;
    float px = (float)(w + (k % 3) - 1) + dx;
    float y0 = floorf(py), x0 = floorf(px);
    s_iy[idx] = (int)y0;
    s_ix[idx] = (int)x0;
    s_wy[idx] = py - y0;
    s_wx[idx] = px - x0;
  }

  float acc[4][8];   // [oi][pi]
#pragma unroll
  for (int a = 0; a < 4; ++a)
#pragma unroll
    for (int b = 0; b < 8; ++b) acc[a][b] = 0.f;

  const float* xbase = xt + (size_t)n * HWH * CC + tid;   // c = tid
  const float4* wt4  = (const float4*)wt;
  float4* wl4        = (float4*)w_lds;

  for (int k = 0; k < 9; ++k) {
    __syncthreads();   // prev tap GEMM done reading val_lds (and s_* ready on k=0)

    // ---- sample tap k for all PPB pixels, this thread's channel c = tid ----
#pragma unroll 4
    for (int p = 0; p < PPB; ++p) {
      int pk = p * 9 + k;
      int iy = s_iy[pk], ix = s_ix[pk];
      float wy = s_wy[pk], wx = s_wx[pk];
      bool y0v = (unsigned)iy < (unsigned)HH;
      bool y1v = (unsigned)(iy + 1) < (unsigned)HH;
      bool x0v = (unsigned)ix < (unsigned)WW;
      bool x1v = (unsigned)(ix + 1) < (unsigned)WW;
      const float* rp = xbase + (iy * WW + ix) * CC;
      float v00 = 0.f, v01 = 0.f, v10 = 0.f, v11 = 0.f;
      if (y0v & x0v) v00 = rp[0];
      if (y0v & x1v) v01 = rp[CC];
      if (y1v & x0v) v10 = rp[WW * CC];
      if (y1v & x1v) v11 = rp[WW * CC + CC];
      float v = v00 * (1.f - wy) * (1.f - wx) + v01 * (1.f - wy) * wx +
                v10 * wy * (1.f - wx) + v11 * wy * wx;
      val_lds[tid * VPAD + p] = v;
    }

    // ---- GEMM for tap k over c-chunks ----
    for (int cc = 0; cc < CC / CCH; ++cc) {
      __syncthreads();   // prev chunk reads done; (cc=0) val_lds writes done
#pragma unroll
      for (int j = 0; j < 8; ++j)
        wl4[tid + j * 256] = wt4[(size_t)k * (CC * OO / 4) + cc * (CCH * OO / 4) + tid + j * 256];
      __syncthreads();
#pragma unroll
      for (int ci = 0; ci < CCH; ++ci) {
        int c = cc * CCH + ci;
        float4 wv = wl4[ci * (OO / 4) + lane];
        float4 va = *(const float4*)(val_lds + c * VPAD + pg * 8);
        float4 vb = *(const float4*)(val_lds + c * VPAD + pg * 8 + 4);
        float vp[8] = {va.x, va.y, va.z, va.w, vb.x, vb.y, vb.z, vb.w};
        float wo[4] = {wv.x, wv.y, wv.z, wv.w};
#pragma unroll
        for (int oi = 0; oi < 4; ++oi)
#pragma unroll
          for (int pi = 0; pi < 8; ++pi) acc[oi][pi] += wo[oi] * vp[pi];
      }
    }
  }

  // ---- store: out[n][o][hw0 + pg*8 + pi] ----
  size_t obase = (size_t)n * OO * HWH + hw0 + pg * 8;
#pragma unroll
  for (int oi = 0; oi < 4; ++oi) {
    int o = lane * 4 + oi;
    float4 s0 = {acc[oi][0], acc[oi][1], acc[oi][2], acc[oi][3]};
    float4 s1 = {acc[oi][4], acc[oi][5], acc[oi][6], acc[oi][7]};
    *(float4*)(out + obase + (size_t)o * HWH)     = s0;
    *(float4*)(out + obase + (size_t)o * HWH + 4) = s1;
  }
}

extern "C" void kernel_launch(void* const* d_in, const int* in_sizes, int n_in,
                              void* d_out, int out_size, void* d_ws, size_t ws_size,
                              hipStream_t stream) {
  const float* x   = (const float*)d_in[0];   // [4,256,64,64]
  const float* off = (const float*)d_in[1];   // [4,4096,18]
  const float* w   = (const float*)d_in[2];   // [256,256,3,3]
  float* out = (float*)d_out;                 // [4,256,64,64]

  float* wt = (float*)d_ws;                   // 589824 floats = 2.36 MB
  float* xt = wt + 589824;                    // 4194304 floats = 16.8 MB

  transpose_w_kernel<<<2304, 256, 0, stream>>>(w, wt);
  dim3 gx(HWH / 32, CC / 32, 4), bx(32, 8);
  transpose_x_kernel<<<gx, bx, 0, stream>>>(x, xt);
  deform_main_kernel<<<(4 * HWH) / PPB, 256, 0, stream>>>(xt, wt, off, out);
}

// Round 3
// 160.483 us; speedup vs baseline: 3.0218x; 3.0218x over previous
//
#include <hip/hip_runtime.h>
#include <hip/hip_bf16.h>

#define CC 256   // input channels
#define OO 256   // output channels
#define HH 64
#define WW 64
#define HWN 4096 // H*W
#define MPB 64   // pixels per block
#define NPB 128  // outputs per block
#define CCH 64   // channel chunk for weight staging
#define VST 264  // val_lds row stride in bf16 elems (256+8)
#define WST 72   // w_lds row stride in bf16 elems (64+8)

typedef __bf16 bf16x8 __attribute__((ext_vector_type(8)));
typedef float f32x4 __attribute__((ext_vector_type(4)));

__device__ __forceinline__ float b2f(unsigned short u) {
  union { unsigned int i; float f; } x;
  x.i = ((unsigned int)u) << 16;
  return x.f;
}
__device__ __forceinline__ unsigned short f2b(float f) {
  __hip_bfloat16 h = __float2bfloat16(f);   // RNE
  unsigned short u;
  __builtin_memcpy(&u, &h, 2);
  return u;
}

// ---------------- transpose x: [N,C,H,W] f32 -> xt [N,H*W,C] bf16 ----------------
__global__ __launch_bounds__(256) void transpose_x_kernel(
    const float* __restrict__ x, unsigned short* __restrict__ xt) {
  __shared__ float tile[32][33];
  int n  = blockIdx.z;
  int c0 = blockIdx.y * 32;
  int s0 = blockIdx.x * 32;
  int tx = threadIdx.x;   // 0..31
  int ty = threadIdx.y;   // 0..7
  const float* xp = x + ((size_t)n * CC + c0) * HWN + s0;
#pragma unroll
  for (int i = ty; i < 32; i += 8)
    tile[i][tx] = xp[(size_t)i * HWN + tx];
  __syncthreads();
  unsigned short* op = xt + ((size_t)n * HWN + s0) * CC + c0;
#pragma unroll
  for (int i = ty; i < 32; i += 8)
    op[(size_t)i * CC + tx] = f2b(tile[tx][i]);
}

// ------------- transpose weight: [O,C,3,3] f32 -> wt [9][O][C] bf16 -------------
__global__ __launch_bounds__(256) void transpose_w_kernel(
    const float* __restrict__ w, unsigned short* __restrict__ wt) {
  int tid = blockIdx.x * 256 + threadIdx.x;   // 0 .. 589823
  int k = tid >> 16;
  int o = (tid >> 8) & 255;
  int c = tid & 255;
  wt[tid] = f2b(w[((size_t)o * CC + c) * 9 + k]);
}

// ---------------- fused deform-sample (bf16) + MFMA GEMM ----------------
// grid: 512 blocks of 256. Block: 64 pixels x 128 outputs.
__global__ __launch_bounds__(256, 2) void deform_mfma_kernel(
    const unsigned short* __restrict__ xt,   // [4][4096][256] bf16
    const unsigned short* __restrict__ wt,   // [9][256][256] bf16  ([k][o][c])
    const float* __restrict__ off,
    float* __restrict__ out) {
  __shared__ unsigned short val_lds[MPB * VST];   // 33792 B  [p][c] bf16
  __shared__ unsigned short w_lds[NPB * WST];     // 18432 B  [o][cj] bf16
  __shared__ int4   s_off[MPB * 9];               // clamped corner offsets
  __shared__ float4 s_w[MPB * 9];                 // masked bilinear weights

  const int tid  = threadIdx.x;
  const int lane = tid & 63;
  const int wv   = tid >> 6;
  const int n15  = lane & 15;
  const int quad = lane >> 4;

  const int bx    = blockIdx.x;
  const int pg    = (bx >> 1) * MPB;
  const int nb    = pg >> 12;
  const int hw0   = pg & (HWN - 1);
  const int obase = (bx & 1) * NPB;

  // ---- precompute per-(pixel,tap) sampling params ----
  for (int idx = tid; idx < MPB * 9; idx += 256) {
    int p = idx / 9;
    int k = idx - p * 9;
    int hw = hw0 + p;
    int h = hw >> 6, w = hw & 63;
    size_t ob = ((size_t)(nb * HWN + hw)) * 18 + 2 * k;
    float dy = off[ob], dx = off[ob + 1];
    float py = (float)(h + k / 3 - 1) + dy;
    float px = (float)(w + k % 3 - 1) + dx;
    float fy = floorf(py), fx = floorf(px);
    int iy = (int)fy, ix = (int)fx;
    float wy = py - fy, wx = px - fx;
    float my0 = ((unsigned)iy       < (unsigned)HH) ? 1.f : 0.f;
    float my1 = ((unsigned)(iy + 1) < (unsigned)HH) ? 1.f : 0.f;
    float mx0 = ((unsigned)ix       < (unsigned)WW) ? 1.f : 0.f;
    float mx1 = ((unsigned)(ix + 1) < (unsigned)WW) ? 1.f : 0.f;
    int iy0 = min(max(iy, 0), HH - 1), iy1 = min(max(iy + 1, 0), HH - 1);
    int ix0 = min(max(ix, 0), WW - 1), ix1 = min(max(ix + 1, 0), WW - 1);
    s_off[idx] = make_int4(iy0 * WW + ix0, iy0 * WW + ix1,
                           iy1 * WW + ix0, iy1 * WW + ix1);
    s_w[idx] = make_float4((1.f - wy) * (1.f - wx) * my0 * mx0,
                           (1.f - wy) * wx         * my0 * mx1,
                           wy         * (1.f - wx) * my1 * mx0,
                           wy         * wx         * my1 * mx1);
  }

  f32x4 acc[4][2];
#pragma unroll
  for (int a = 0; a < 4; ++a)
#pragma unroll
    for (int b = 0; b < 2; ++b) acc[a][b] = (f32x4){0.f, 0.f, 0.f, 0.f};

  const unsigned short* xb = xt + (size_t)nb * HWN * CC + lane * 4;  // c = lane*4..+3

  for (int k = 0; k < 9; ++k) {
    __syncthreads();   // prev tap's A-frag reads of val_lds done; s_* ready at k=0

    // ---- sample tap k: 64 px x 256 c bf16 into val_lds ----
#pragma unroll 2
    for (int i = 0; i < 16; ++i) {
      int p = wv + i * 4;              // all lanes of wave share p -> broadcast param reads
      int idx = p * 9 + k;
      int4   o4 = s_off[idx];
      float4 w4 = s_w[idx];
      ushort4 v00 = *(const ushort4*)(xb + (size_t)o4.x * CC);
      ushort4 v01 = *(const ushort4*)(xb + (size_t)o4.y * CC);
      ushort4 v10 = *(const ushort4*)(xb + (size_t)o4.z * CC);
      ushort4 v11 = *(const ushort4*)(xb + (size_t)o4.w * CC);
      ushort4 r;
      r.x = f2b(w4.x * b2f(v00.x) + w4.y * b2f(v01.x) + w4.z * b2f(v10.x) + w4.w * b2f(v11.x));
      r.y = f2b(w4.x * b2f(v00.y) + w4.y * b2f(v01.y) + w4.z * b2f(v10.y) + w4.w * b2f(v11.y));
      r.z = f2b(w4.x * b2f(v00.z) + w4.y * b2f(v01.z) + w4.z * b2f(v10.z) + w4.w * b2f(v11.z));
      r.w = f2b(w4.x * b2f(v00.w) + w4.y * b2f(v01.w) + w4.z * b2f(v10.w) + w4.w * b2f(v11.w));
      *(ushort4*)(val_lds + p * VST + lane * 4) = r;
    }

    // ---- GEMM for tap k over 64-channel chunks ----
    const unsigned short* wg = wt + ((size_t)k * OO + obase) * CC;
    for (int cc = 0; cc < CC / CCH; ++cc) {
      __syncthreads();   // prev chunk B-reads done
      {
        // stage 128 rows x 64 ch: each thread copies 32 bf16 = 4 x b128
        int o = tid >> 1, cj0 = (tid & 1) * 32;
        const uint4* src = (const uint4*)(wg + (size_t)o * CC + cc * CCH + cj0);
        uint4* dst = (uint4*)(w_lds + o * WST + cj0);
        dst[0] = src[0];
        dst[1] = src[1];
        dst[2] = src[2];
        dst[3] = src[3];
      }
      __syncthreads();   // w_lds staged; also orders val_lds writes before A-reads (cc==0)
#pragma unroll
      for (int ks = 0; ks < 2; ++ks) {
        int cbase = cc * CCH + ks * 32;
        bf16x8 afr[4], bfr[2];
#pragma unroll
        for (int mt = 0; mt < 4; ++mt)
          afr[mt] = *(const bf16x8*)(val_lds + (mt * 16 + n15) * VST + cbase + quad * 8);
#pragma unroll
        for (int nt = 0; nt < 2; ++nt)
          bfr[nt] = *(const bf16x8*)(w_lds + (wv * 32 + nt * 16 + n15) * WST + ks * 32 + quad * 8);
#pragma unroll
        for (int mt = 0; mt < 4; ++mt)
#pragma unroll
          for (int nt = 0; nt < 2; ++nt)
            acc[mt][nt] = __builtin_amdgcn_mfma_f32_16x16x32_bf16(
                afr[mt], bfr[nt], acc[mt][nt], 0, 0, 0);
      }
    }
  }

  // ---- epilogue: D: col=lane&15 -> o, row=quad*4+reg -> pixel ----
#pragma unroll
  for (int mt = 0; mt < 4; ++mt)
#pragma unroll
    for (int nt = 0; nt < 2; ++nt) {
      int o  = obase + wv * 32 + nt * 16 + n15;
      int px = hw0 + mt * 16 + quad * 4;
      float4 v = {acc[mt][nt][0], acc[mt][nt][1], acc[mt][nt][2], acc[mt][nt][3]};
      *(float4*)(out + ((size_t)nb * OO + o) * HWN + px) = v;
    }
}

extern "C" void kernel_launch(void* const* d_in, const int* in_sizes, int n_in,
                              void* d_out, int out_size, void* d_ws, size_t ws_size,
                              hipStream_t stream) {
  const float* x   = (const float*)d_in[0];   // [4,256,64,64]
  const float* off = (const float*)d_in[1];   // [4,4096,18]
  const float* w   = (const float*)d_in[2];   // [256,256,3,3]
  float* out = (float*)d_out;                 // [4,256,64,64]

  unsigned short* wt = (unsigned short*)d_ws;           // 589824 bf16
  unsigned short* xt = wt + 589824;                     // 4194304 bf16

  transpose_w_kernel<<<2304, 256, 0, stream>>>(w, wt);
  dim3 gx(HWN / 32, CC / 32, 4), bx(32, 8);
  transpose_x_kernel<<<gx, bx, 0, stream>>>(x, xt);
  deform_mfma_kernel<<<512, 256, 0, stream>>>(xt, wt, off, out);
}